// Round 3
// baseline (37.513 us; speedup 1.0000x reference)
//
#include <hip/hip_runtime.h>
#include <math.h>

// NonLinearLayer: piecewise-quadratic CDF flow on a geometric mesh.
// x:(N,16) f32, pdj:(N,1), sldj:(N,1), log_p:(63,16), mesh_norm:(65,), elmt_size:(64,)
// out = concat(x_out (N*16), pdj_out (N), sldj_out (N))
//
// Bin index is computed ANALYTICALLY (mesh is geometric: boundary i at
// 1+K1*|x| = 1.2^|i|). No searchsorted fixup: y and abs_det are continuous
// across bin boundaries, so a +-1 misclassification (only possible within
// ~2 ulp of a boundary) perturbs the output at the 1e-5 level.

namespace {
constexpr int DIM = 16;
constexpr int ME  = 64;
constexpr float BOUNDF = 50.0f;
// K1 = 0.2/one_step = 0.02*(1.2^32-1);  INV_L2R = 1/log2(1.2)
constexpr float K1      = 6.8164378f;
constexpr float INV_L2R = 3.8017840f;
constexpr int COEF_FLOATS = ME * 68;                 // (A,B,D,2A)[bin][dim], stride 68 floats
constexpr int EP_BASE     = COEF_FLOATS - 63 * DIM;  // 3344: transient exp(log_p) scratch
}

__global__ __launch_bounds__(256) void nll_kernel(
    const float* __restrict__ x,
    const float* __restrict__ pdj,
    const float* __restrict__ sldj,
    const float* __restrict__ log_p,
    const float* __restrict__ mesh_norm,
    float* __restrict__ out,
    int npts)
{
  __shared__ __align__(16) float co[COEF_FLOATS];
  __shared__ float s_mesh[ME + 1];

  const int tid = threadIdx.x;

  // ---- phase 1: loads + exp (fully parallel) ----
  if (tid <= ME) s_mesh[tid] = mesh_norm[tid];
  for (int i = tid; i < 63 * DIM; i += 256)
    co[EP_BASE + i] = __expf(log_p[i]);
  __syncthreads();

  // ---- phase 2a: stash this wave's ep columns in regs (ep region gets
  //      overwritten by coef writes in 2b; barrier orders all waves) ----
  const int wv = tid >> 6, lane = tid & 63;
  float epv[4];
#pragma unroll
  for (int i = 0; i < 4; ++i)
    epv[i] = (lane < 63) ? co[EP_BASE + lane * DIM + (4 * wv + i)] : 0.f;
  const float mj  = s_mesh[lane];
  const float mj1 = s_mesh[lane + 1];
  const float mj2 = s_mesh[(lane + 2 > ME) ? ME : (lane + 2)];
  const float es0 = s_mesh[1] - s_mesh[0];
  __syncthreads();

  // ---- phase 2b: wave-parallel normalize+scan, 4 dims per wave ----
  const float h = mj1 - mj;
#pragma unroll
  for (int i = 0; i < 4; ++i) {
    const int d = 4 * wv + i;
    const float ep = epv[i];
    float ss = (lane < 63) ? ep * (mj2 - mj) : 0.f;
    ss += __shfl_xor(ss, 1);  ss += __shfl_xor(ss, 2);  ss += __shfl_xor(ss, 4);
    ss += __shfl_xor(ss, 8);  ss += __shfl_xor(ss, 16); ss += __shfl_xor(ss, 32);
    const float scale = (1.0f - es0) / (0.5f * ss);
    const float cur = (lane < 63) ? ep * scale : 1.0f;   // pdf_norm[lane+1]
    float prev = __shfl_up(cur, 1);                       // pdf_norm[lane]
    if (lane == 0) prev = 1.0f;
    const float cell = (prev + cur) * 0.5f * h;
    float v = cell, o;
    o = __shfl_up(v, 1);  if (lane >= 1)  v += o;
    o = __shfl_up(v, 2);  if (lane >= 2)  v += o;
    o = __shfl_up(v, 4);  if (lane >= 4)  v += o;
    o = __shfl_up(v, 8);  if (lane >= 8)  v += o;
    o = __shfl_up(v, 16); if (lane >= 16) v += o;
    o = __shfl_up(v, 32); if (lane >= 32) v += o;
    const float F = v - cell;                             // exclusive prefix = F_ref[lane]
    const float A = 0.5f * (cur - prev) / h;
    const float B = fmaf(-(A + A), mj, prev);
    const float D = fmaf(mj, fmaf(mj, A, -prev), F);
    *reinterpret_cast<float4*>(&co[lane * 68 + 4 * d]) = make_float4(A, B, D, A + A);
  }
  __syncthreads();

  // ---- main loop: one full point (16 dims) per thread ----
  const int stride = gridDim.x * blockDim.x;
  const float4* __restrict__ x4 = reinterpret_cast<const float4*>(x);
  float4* __restrict__ out4 = reinterpret_cast<float4*>(out);
  const int np16 = npts * DIM;

  for (int p = blockIdx.x * blockDim.x + tid; p < npts; p += stride) {
    float4 X[4];
#pragma unroll
    for (int q = 0; q < 4; ++q) X[q] = x4[4 * p + q];
    const float* vals = reinterpret_cast<const float*>(X);
    float yv[16];
    float prod = 1.f;

#pragma unroll
    for (int j = 0; j < 16; ++j) {
      const float val = vals[j];
      const float xn = (val + BOUNDF) * 0.01f;
      const float u = fmaf(fabsf(val), K1, 1.0f);
      const float n = __log2f(u) * INV_L2R;
      const int k32 = (int)ceilf(copysignf(n, val));      // k-32 in [-32,32]
      int km1 = k32 + 31;
      km1 = km1 < 0 ? 0 : (km1 > 63 ? 63 : km1);
      const float4 cf = *reinterpret_cast<const float4*>(&co[km1 * 68 + 4 * j]); // (A,B,D,2A)
      float y  = fmaf(xn, fmaf(xn, cf.x, cf.y), cf.z);
      float dt = fmaf(xn, cf.w, cf.y);
      const bool cover = (xn > 0.f) && (xn <= 1.0f);
      y  = cover ? y  : xn;
      dt = cover ? dt : 1.0f;
      yv[j] = fmaf(y, 2.0f * BOUNDF, -BOUNDF);
      prod *= dt;
    }

    float4* o4 = &out4[4 * p];
#pragma unroll
    for (int q = 0; q < 4; ++q)
      o4[q] = make_float4(yv[4 * q], yv[4 * q + 1], yv[4 * q + 2], yv[4 * q + 3]);
    out[np16 + p]        = pdj[p] * prod;
    out[np16 + npts + p] = sldj[p] + __logf(prod);
  }
}

extern "C" void kernel_launch(void* const* d_in, const int* in_sizes, int n_in,
                              void* d_out, int out_size, void* d_ws, size_t ws_size,
                              hipStream_t stream) {
  const float* x    = (const float*)d_in[0];
  const float* pdj  = (const float*)d_in[1];
  const float* sldj = (const float*)d_in[2];
  const float* lp   = (const float*)d_in[3];
  const float* mesh = (const float*)d_in[4];
  float* out = (float*)d_out;

  const int npts  = in_sizes[0] / DIM;
  const int block = 256;
  int grid = 2048;
  const int needed = (npts + block - 1) / block;
  if (needed < grid) grid = needed;

  hipLaunchKernelGGL(nll_kernel, dim3(grid), dim3(block), 0, stream,
                     x, pdj, sldj, lp, mesh, out, npts);
}

// Round 4
// 33.940 us; speedup vs baseline: 1.1053x; 1.1053x over previous
//
#include <hip/hip_runtime.h>
#include <math.h>

// NonLinearLayer: piecewise-quadratic CDF flow on a geometric mesh.
// x:(N,16) f32, pdj:(N,1), sldj:(N,1), log_p:(63,16), mesh_norm:(65,), elmt_size:(64,)
// out = concat(x_out (N*16), pdj_out (N), sldj_out (N))
//
// Bin index computed ANALYTICALLY (mesh geometric: boundary i at 1+K1*|x|=1.2^|i|).
// No searchsorted fixup: y and abs_det are continuous across bin boundaries, so a
// +-1 misclassification (only within ~2ulp of a boundary) perturbs output ~1e-5.
//
// Inner loop is 3 explicit phases (index calc / 8 batched ds_read_b128 / math)
// so the LDS gathers overlap instead of serializing (R3 lesson: VGPR=32 meant
// the compiler round-tripped each gather; force a wide load window).

namespace {
constexpr int DIM = 16;
constexpr int ME  = 64;
constexpr float BOUNDF = 50.0f;
// K1 = 0.2/one_step = 0.02*(1.2^32-1);  INV_L2R = 1/log2(1.2)
constexpr float K1      = 6.8164378f;
constexpr float INV_L2R = 3.8017840f;
constexpr int COEF_FLOATS = ME * 68;                 // (A,B,D,2A)[bin][dim], stride 68 floats
constexpr int EP_BASE     = COEF_FLOATS - 63 * DIM;  // transient exp(log_p) scratch in tail
}

__global__ __launch_bounds__(256) void nll_kernel(
    const float* __restrict__ x,
    const float* __restrict__ pdj,
    const float* __restrict__ sldj,
    const float* __restrict__ log_p,
    const float* __restrict__ mesh_norm,
    float* __restrict__ out,
    int npts, int npairs)
{
  __shared__ __align__(16) float co[COEF_FLOATS];
  __shared__ float s_mesh[ME + 1];

  const int tid = threadIdx.x;

  // ---- phase 1: loads + exp (fully parallel) ----
  if (tid <= ME) s_mesh[tid] = mesh_norm[tid];
  for (int i = tid; i < 63 * DIM; i += 256)
    co[EP_BASE + i] = __expf(log_p[i]);
  __syncthreads();

  // ---- phase 2a: stash ep columns in regs (scratch gets overwritten in 2b) ----
  const int wv = tid >> 6, lane = tid & 63;
  float epv[4];
#pragma unroll
  for (int i = 0; i < 4; ++i)
    epv[i] = (lane < 63) ? co[EP_BASE + lane * DIM + (4 * wv + i)] : 0.f;
  const float mj  = s_mesh[lane];
  const float mj1 = s_mesh[lane + 1];
  const float mj2 = s_mesh[(lane + 2 > ME) ? ME : (lane + 2)];
  const float es0 = s_mesh[1] - s_mesh[0];
  __syncthreads();

  // ---- phase 2b: wave-parallel normalize + prefix scan, 4 dims per wave ----
  const float h = mj1 - mj;
#pragma unroll
  for (int i = 0; i < 4; ++i) {
    const int d = 4 * wv + i;
    const float ep = epv[i];
    float ss = (lane < 63) ? ep * (mj2 - mj) : 0.f;
    ss += __shfl_xor(ss, 1);  ss += __shfl_xor(ss, 2);  ss += __shfl_xor(ss, 4);
    ss += __shfl_xor(ss, 8);  ss += __shfl_xor(ss, 16); ss += __shfl_xor(ss, 32);
    const float scale = (1.0f - es0) / (0.5f * ss);
    const float cur = (lane < 63) ? ep * scale : 1.0f;   // pdf_norm[lane+1]
    float prev = __shfl_up(cur, 1);                       // pdf_norm[lane]
    if (lane == 0) prev = 1.0f;
    const float cell = (prev + cur) * 0.5f * h;
    float v = cell, o;
    o = __shfl_up(v, 1);  if (lane >= 1)  v += o;
    o = __shfl_up(v, 2);  if (lane >= 2)  v += o;
    o = __shfl_up(v, 4);  if (lane >= 4)  v += o;
    o = __shfl_up(v, 8);  if (lane >= 8)  v += o;
    o = __shfl_up(v, 16); if (lane >= 16) v += o;
    o = __shfl_up(v, 32); if (lane >= 32) v += o;
    const float F = v - cell;                             // exclusive prefix = F_ref[lane]
    const float A = 0.5f * (cur - prev) / h;
    const float B = fmaf(-(A + A), mj, prev);
    const float D = fmaf(mj, fmaf(mj, A, -prev), F);
    *reinterpret_cast<float4*>(&co[lane * 68 + 4 * d]) = make_float4(A, B, D, A + A);
  }
  __syncthreads();

  // ---- main loop: 8 elements (half a point) per thread ----
  const int tpg = gridDim.x * blockDim.x;
  const float4* __restrict__ x4 = reinterpret_cast<const float4*>(x);
  float4* __restrict__ out4 = reinterpret_cast<float4*>(out);
  const int np16 = npts * DIM;

  for (int t = blockIdx.x * blockDim.x + tid; t < npairs; t += tpg) {
    const int p  = t >> 1;
    const int hh = t & 1;              // half: dims hh*8 .. hh*8+7
    const float4 xa = x4[2 * t];
    const float4 xb = x4[2 * t + 1];
    const float ps = hh ? sldj[p] : pdj[p];   // branch-free scalar load
    const float vals[8] = {xa.x, xa.y, xa.z, xa.w, xb.x, xb.y, xb.z, xb.w};

    // phase A: indices (pure VALU, 8 independent chains)
    float xn[8];
    int   off[8];
#pragma unroll
    for (int j = 0; j < 8; ++j) {
      const float val = vals[j];
      xn[j] = (val + BOUNDF) * 0.01f;
      const float u = fmaf(fabsf(val), K1, 1.0f);
      const float n = __log2f(u) * INV_L2R;
      int km1 = 31 + (int)ceilf(copysignf(n, val));
      km1 = km1 < 0 ? 0 : (km1 > 63 ? 63 : km1);
      off[j] = km1 * 68 + (((hh << 3) + j) << 2);
    }

    // phase B: 8 batched LDS gathers (independent -> all in flight)
    float4 cf[8];
#pragma unroll
    for (int j = 0; j < 8; ++j)
      cf[j] = *reinterpret_cast<const float4*>(&co[off[j]]);

    // phase C: math + pairwise product tree
    float yv[8], dt[8];
#pragma unroll
    for (int j = 0; j < 8; ++j) {
      const float z = xn[j];
      float y = fmaf(z, fmaf(z, cf[j].x, cf[j].y), cf[j].z);
      float d = fmaf(z, cf[j].w, cf[j].y);
      const bool cover = (z > 0.f) && (z <= 1.0f);
      y = cover ? y : z;
      d = cover ? d : 1.0f;
      yv[j] = fmaf(y, 2.0f * BOUNDF, -BOUNDF);
      dt[j] = d;
    }
    const float prod = ((dt[0] * dt[1]) * (dt[2] * dt[3])) *
                       ((dt[4] * dt[5]) * (dt[6] * dt[7]));

    out4[2 * t]     = make_float4(yv[0], yv[1], yv[2], yv[3]);
    out4[2 * t + 1] = make_float4(yv[4], yv[5], yv[6], yv[7]);

    const float full = prod * __shfl_xor(prod, 1);
    const float res  = hh ? (ps + __logf(full)) : (ps * full);
    out[np16 + hh * npts + p] = res;
  }
}

extern "C" void kernel_launch(void* const* d_in, const int* in_sizes, int n_in,
                              void* d_out, int out_size, void* d_ws, size_t ws_size,
                              hipStream_t stream) {
  const float* x    = (const float*)d_in[0];
  const float* pdj  = (const float*)d_in[1];
  const float* sldj = (const float*)d_in[2];
  const float* lp   = (const float*)d_in[3];
  const float* mesh = (const float*)d_in[4];
  float* out = (float*)d_out;

  const int npts   = in_sizes[0] / DIM;
  const int npairs = npts * 2;
  const int block  = 256;
  int grid = 2048;
  const int needed = (npairs + block - 1) / block;
  if (needed < grid) grid = needed;

  hipLaunchKernelGGL(nll_kernel, dim3(grid), dim3(block), 0, stream,
                     x, pdj, sldj, lp, mesh, out, npts, npairs);
}